// Round 2
// baseline (883.712 us; speedup 1.0000x reference)
//
#include <hip/hip_runtime.h>
#include <hip/hip_fp16.h>

// Meta-linear, DEPTH=2, factored as two streams per depth:
//   Stage 1: V[oi, b] = sum_k f16(W[oi,k]) * f16(x[b,k]/sqrt(d))   (GEMM, W streamed
//            SEQUENTIALLY row-major: each block = 256 contiguous oi rows = 512 KB region)
//   Stage 2: out[b,o] = sum_i V[o*512+i, b] * x[b,i] + bias[o]     (streaming reduce)
// Rationale: previous kernel read W as 256B chunks at 2KB stride (k-tiled grid) ->
// 1.3 TB/s effective DRAM. Harness fills prove 6.4 TB/s on sequential. This version
// makes every W access a 1 KB-contiguous per-instruction run inside per-block
// contiguous 512 KB windows. B-operand fragments are precomputed (128 KB, L2-resident).

typedef __attribute__((ext_vector_type(8))) _Float16 f16x8;
typedef __attribute__((ext_vector_type(4))) float    f32x4v;
typedef __attribute__((ext_vector_type(2))) unsigned u32x2;
typedef __attribute__((ext_vector_type(4))) unsigned u32x4;

#define DD 512
#define BB 128
#define INV_SQRT_D 0.04419417382415922f   // 1/sqrt(512)

static __device__ __forceinline__ unsigned pkh(float a, float b) {
    __half2 h = __float22half2_rn(make_float2(a, b));
    unsigned u; __builtin_memcpy(&u, &h, sizeof(u)); return u;
}
static __device__ __forceinline__ u32x4 pack8(f32x4v a, f32x4v b) {
    u32x4 r; r.x = pkh(a.x, a.y); r.y = pkh(a.z, a.w);
             r.z = pkh(b.x, b.y); r.w = pkh(b.z, b.w); return r;
}
static __device__ __forceinline__ f16x8 as_h8(u32x4 q) {
    f16x8 v; __builtin_memcpy(&v, &q, sizeof(v)); return v;
}
static __device__ __forceinline__ float2 h2f(unsigned u) {
    __half2 h; __builtin_memcpy(&h, &u, 4); return __half22float2(h);
}

// ---------- prep: build xhf (B-operand fragments, f16, scaled) + xT (fp32 transpose) ----
// xhf entry e = (kw*8 + nf)*64 + lane : f16x8 of x[b = nf*16+(lane&15),
//               k = kw*32 + (lane>>4)*8 .. +7] * (1/sqrt(d))   (MFMA B-frag layout)
// xT[i*128 + b] = x[b][i]  (fp32, stage-2 x-factor, L2-resident)
__global__ void prep(const float* __restrict__ x, u32x4* __restrict__ xhf,
                     float* __restrict__ xT) {
    const int t = blockIdx.x * 256 + threadIdx.x;
    if (t < 8192) {
        const int lane = t & 63, fid = t >> 6;
        const int kw = fid >> 3, nf = fid & 7;
        const int b  = nf * 16 + (lane & 15);
        const int k0 = kw * 32 + (lane >> 4) * 8;
        const float* xr = x + b * DD + k0;
        f32x4v a = *(const f32x4v*)(xr)     * INV_SQRT_D;
        f32x4v c = *(const f32x4v*)(xr + 4) * INV_SQRT_D;
        xhf[t] = pack8(a, c);
    } else {
        const int u = t - 8192;            // 0..16383
        const int i = u >> 5, c4 = u & 31; // i row, 4-col group of b
        f32x4v v;
        v.x = x[(c4 * 4 + 0) * DD + i];
        v.y = x[(c4 * 4 + 1) * DD + i];
        v.z = x[(c4 * 4 + 2) * DD + i];
        v.w = x[(c4 * 4 + 3) * DD + i];
        *(f32x4v*)(xT + i * BB + c4 * 4) = v;
    }
}

// ---------- stage 1: V[oi, b] GEMM, W streamed sequentially -----------------------------
// Grid 1024 x 256 threads. Block: 256 consecutive oi rows (contiguous 512 KB of W),
// 8 slabs of 32 rows. Per slab: wave w stages rows w*8..+8 (16 KB contiguous, 16 x 1KB
// instrs) -> f16 XOR-swizzled LDS; 16 kw-steps x (2 A ds_reads + 2 B L2 loads + 4 MFMA);
// epilogue transposes C frags through LDS -> contiguous 8 KB f16 V store.
// LDS 48 KB -> 3 blocks/CU.
__global__ __launch_bounds__(256, 2)
void s1_gemm(const float* __restrict__ W, const u32x4* __restrict__ xhf,
             unsigned* __restrict__ V32) {
    __shared__ u32x4    abuf[2048];        // 32 KB: 32 rows x 64 x 16B f16, XOR-swizzled
    __shared__ unsigned vbuf[2][2048];     // 16 KB: dbuf 32 rows x 64 u32 (= 128 f16 b)

    const int tid  = threadIdx.x;
    const int lane = tid & 63;
    const int wv   = tid >> 6;
    const int l15  = lane & 15;
    const int quad = lane >> 4;
    const int sw   = l15 & 7;

    const long rowbase = (long)blockIdx.x * 256;
    // stage instr j (0..15): row = wv*8 + (j>>1), half = j&1 covers k in [half*256, +256)
    // lane l: 16 B at float-index row*512 + half*256 + l*4  -> contiguous 1 KB per instr
    const float* wp = W + rowbase * DD + (wv * 8) * DD + lane * 4;

    f32x4v g[16];
#pragma unroll
    for (int j = 0; j < 16; ++j)
        g[j] = *(const f32x4v*)(wp + (j >> 1) * DD + (j & 1) * 256);
#pragma unroll
    for (int j = 0; j < 16; ++j) {
        const int row = wv * 8 + (j >> 1);
        const int c8  = (j & 1) * 64 + lane;     // 8B f16 chunk (4 k) within row
        const int c16 = c8 >> 1;
        ((u32x2*)abuf)[(row * 64 + (c16 ^ (row & 7))) * 2 + (c8 & 1)] =
            (u32x2){pkh(g[j].x, g[j].y), pkh(g[j].z, g[j].w)};
    }

    unsigned lic = 0;   // opaque 0: keeps xhf B-frag loads per-slab (no 128-VGPR hoist)
#pragma unroll 1
    for (int s = 0; s < 8; ++s) {
        asm volatile("" : "+v"(lic));
        __syncthreads();   // abuf(slab s) ready; vbuf[s&1] free

        if (s < 7) {       // T14: issue next slab's loads before compute
            const float* wps = wp + (long)(s + 1) * 32 * DD;
#pragma unroll
            for (int j = 0; j < 16; ++j)
                g[j] = *(const f32x4v*)(wps + (j >> 1) * DD + (j & 1) * 256);
        }

        f32x4v c00 = {0,0,0,0}, c01 = {0,0,0,0}, c10 = {0,0,0,0}, c11 = {0,0,0,0};
        const u32x4* bp  = xhf + (wv * 2) * 64 + lane + lic;
        const u32x4* a0p = abuf + l15 * 64;
        const u32x4* a1p = abuf + (16 + l15) * 64;
#pragma unroll 4
        for (int kw = 0; kw < 16; ++kw) {
            f16x8 b0 = as_h8(bp[(kw * 8 + 0) * 64]);         // b cols wv*32 + 0..15
            f16x8 b1 = as_h8(bp[(kw * 8 + 1) * 64]);         // b cols wv*32 + 16..31
            f16x8 a0 = as_h8(a0p[(kw * 4 + quad) ^ sw]);     // rows l15,    k kw*32+quad*8
            f16x8 a1 = as_h8(a1p[(kw * 4 + quad) ^ sw]);     // rows 16+l15
            c00 = __builtin_amdgcn_mfma_f32_16x16x32_f16(a0, b0, c00, 0, 0, 0);
            c01 = __builtin_amdgcn_mfma_f32_16x16x32_f16(a0, b1, c01, 0, 0, 0);
            c10 = __builtin_amdgcn_mfma_f32_16x16x32_f16(a1, b0, c10, 0, 0, 0);
            c11 = __builtin_amdgcn_mfma_f32_16x16x32_f16(a1, b1, c11, 0, 0, 0);
        }

        // epilogue: C/D (col=l15 -> b, row=quad*4+reg -> oi) -> vbuf f16 [row][128 b]
        unsigned short* vb = (unsigned short*)vbuf[s & 1];
        const int bcol = wv * 32 + l15;
#pragma unroll
        for (int r = 0; r < 4; ++r) {
            const int rw0 = (quad * 4 + r) * BB;
            const int rw1 = (16 + quad * 4 + r) * BB;
            __half h;
            h = __float2half_rn(c00[r]); __builtin_memcpy(&vb[rw0 + bcol],      &h, 2);
            h = __float2half_rn(c01[r]); __builtin_memcpy(&vb[rw0 + bcol + 16], &h, 2);
            h = __float2half_rn(c10[r]); __builtin_memcpy(&vb[rw1 + bcol],      &h, 2);
            h = __float2half_rn(c11[r]); __builtin_memcpy(&vb[rw1 + bcol + 16], &h, 2);
        }

        __syncthreads();   // vbuf[s&1] complete; all abuf reads done

        if (s < 7) {       // write next slab into abuf (loads drained here)
#pragma unroll
            for (int j = 0; j < 16; ++j) {
                const int row = wv * 8 + (j >> 1);
                const int c8  = (j & 1) * 64 + lane;
                const int c16 = c8 >> 1;
                ((u32x2*)abuf)[(row * 64 + (c16 ^ (row & 7))) * 2 + (c8 & 1)] =
                    (u32x2){pkh(g[j].x, g[j].y), pkh(g[j].z, g[j].w)};
            }
        }

        // V store: wave w -> rows wv*8..+8 of slab, 2 KB contiguous per wave
        const unsigned* vbr = vbuf[s & 1];
        unsigned* vout = V32 + (rowbase + s * 32 + wv * 8) * 64 + lane;
#pragma unroll
        for (int r = 0; r < 8; ++r)
            vout[r * 64] = vbr[(wv * 8 + r) * 64 + lane];
    }
}

// ---------- stage 2: out[b,o] = sum_i V[o*512+i, b] * xT[i, b] + bias[o] ---------------
// 512 blocks (one o each), stream 128 KB contiguous V + L2-hot xT.
__global__ __launch_bounds__(256, 2)
void s2_reduce(const unsigned* __restrict__ V32, const float* __restrict__ xT,
               const float* __restrict__ bias, float* __restrict__ out) {
    __shared__ float2 red[4][64];
    const int tid = threadIdx.x, lane = tid & 63, wv = tid >> 6;
    const int o = blockIdx.x;
    // lane covers b = 2*lane, 2*lane+1 ; wave wv covers i = wv + 4*m
    const unsigned* vp = V32 + (long)o * DD * 64 + wv * 64 + lane;
    const float*    xp = xT + wv * BB + 2 * lane;

    float2 a0 = {0,0}, a1 = {0,0}, a2 = {0,0}, a3 = {0,0};
#pragma unroll 2
    for (int n = 0; n < 32; ++n) {
        unsigned v0 = vp[(4 * n + 0) * 256];
        unsigned v1 = vp[(4 * n + 1) * 256];
        unsigned v2 = vp[(4 * n + 2) * 256];
        unsigned v3 = vp[(4 * n + 3) * 256];
        float2 x0 = *(const float2*)(xp + (4 * n + 0) * 512);
        float2 x1 = *(const float2*)(xp + (4 * n + 1) * 512);
        float2 x2 = *(const float2*)(xp + (4 * n + 2) * 512);
        float2 x3 = *(const float2*)(xp + (4 * n + 3) * 512);
        float2 f;
        f = h2f(v0); a0.x += f.x * x0.x; a0.y += f.y * x0.y;
        f = h2f(v1); a1.x += f.x * x1.x; a1.y += f.y * x1.y;
        f = h2f(v2); a2.x += f.x * x2.x; a2.y += f.y * x2.y;
        f = h2f(v3); a3.x += f.x * x3.x; a3.y += f.y * x3.y;
    }
    float2 acc;
    acc.x = (a0.x + a1.x) + (a2.x + a3.x);
    acc.y = (a0.y + a1.y) + (a2.y + a3.y);
    red[wv][lane] = acc;
    __syncthreads();
    if (wv == 0) {
        float2 s0 = red[0][lane], s1 = red[1][lane], s2 = red[2][lane], s3 = red[3][lane];
        float sx = (s0.x + s1.x) + (s2.x + s3.x);
        float sy = (s0.y + s1.y) + (s2.y + s3.y);
        float bo = bias[o];
        out[(2 * lane)     * DD + o] = sx + bo;
        out[(2 * lane + 1) * DD + o] = sy + bo;
    }
}

extern "C" void kernel_launch(void* const* d_in, const int* in_sizes, int n_in,
                              void* d_out, int out_size, void* d_ws, size_t ws_size,
                              hipStream_t stream) {
    (void)in_sizes; (void)n_in; (void)out_size; (void)ws_size;

    const float* x    = (const float*)d_in[0];
    const float* W    = (const float*)d_in[1];
    const float* bias = (const float*)d_in[2];
    float* out = (float*)d_out;

    unsigned* V32 = (unsigned*)d_ws;                                   // 67.1 MB (f16 pairs)
    u32x4*    xhf = (u32x4*)((char*)d_ws + (size_t)262144 * 64 * 4);   // 128 KB
    float*    xT  = (float*)((char*)xhf + 8192 * sizeof(u32x4));       // 256 KB
    float*    x1  = xT + DD * BB;                                      // 256 KB

    prep<<<96, 256, 0, stream>>>(x, xhf, xT);
    s1_gemm<<<1024, 256, 0, stream>>>(W, xhf, V32);
    s2_reduce<<<512, 256, 0, stream>>>(V32, xT, bias, x1);

    prep<<<96, 256, 0, stream>>>(x1, xhf, xT);
    s1_gemm<<<1024, 256, 0, stream>>>(W, xhf, V32);
    s2_reduce<<<512, 256, 0, stream>>>(V32, xT, bias, out);
}